// Round 3
// baseline (125.539 us; speedup 1.0000x reference)
//
#include <hip/hip_runtime.h>

typedef __attribute__((ext_vector_type(8))) short bf16x8;
typedef __attribute__((ext_vector_type(4))) float f32x4;
typedef __attribute__((ext_vector_type(4))) unsigned int u32x4;
typedef __attribute__((ext_vector_type(2))) unsigned int u32x2;

namespace {
constexpr int OUT0 = 2 * 32 * 16384;  // offset of att_mp inside d_out
}

// f32 -> bf16 RNE (pre-shift: result in high 16 bits)
__device__ __forceinline__ unsigned int bf16_rne(float f) {
  unsigned int u = __builtin_bit_cast(unsigned int, f);
  return u + 0x7fffu + ((u >> 16) & 1u);
}
// f32 -> bf16 round-half-up (1 VALU; tie-bias only)
__device__ __forceinline__ unsigned int bf16_rhu(float f) {
  return __builtin_bit_cast(unsigned int, f) + 0x8000u;
}
__device__ __forceinline__ unsigned int pack_rne(float lo, float hi) {
  return __builtin_amdgcn_perm(bf16_rne(hi), bf16_rne(lo), 0x07060302u);
}
__device__ __forceinline__ unsigned int pack_rhu(float lo, float hi) {
  return __builtin_amdgcn_perm(bf16_rhu(hi), bf16_rhu(lo), 0x07060302u);
}
__device__ __forceinline__ float bf16_to_f32(unsigned int u16v) {
  return __builtin_bit_cast(float, u16v << 16);
}

// Prep: (a) pack w3 into per-lane bf16 B-fragments for mfma_f32_16x16x32_bf16:
//   u32x4 index = ij*128 + oh*64 + lane; dword d: B[k0][o],B[k0+1][o],
//   k(=c) = (lane>>4)*8 + 2d, o = oh*16 + (lane&15).
// (b) wk[c*9+dd] = sum_o w2[o]*w1[o,c,dd]; wk[288] = w2.b1 + b2.
// NOTE (R1 post-mortem): single-kernel fusion with flag sync regressed 89->179us
// -- agent-scope fences/acquires on gfx950 do L2 writeback+invalidate (per-XCD
// L2 non-coherent), stalling every block. Two-kernel split is structurally
// cheaper; do not re-fuse without a coherence-free scheme.
__global__ __launch_bounds__(256) void prep_kernel(
    const float* __restrict__ w1, const float* __restrict__ b1,
    const float* __restrict__ w2, const float* __restrict__ b2,
    const float* __restrict__ w3,
    float* __restrict__ wk, unsigned int* __restrict__ w3f) {
  int t = threadIdx.x, blk = blockIdx.x;
  if (blk < 98) {
    int f = blk * 256 + t;          // dword index, f < 25088
    int d = f & 3;
    int lane = (f >> 2) & 63;
    int nt = (f >> 8) & 1;
    int ij = f >> 9;                // 0..48
    int o = nt * 16 + (lane & 15);
    int k0 = ((lane >> 4) << 3) + 2 * d;
    float f0 = w3[o * 1568 + k0 * 49 + ij];
    float f1 = w3[o * 1568 + (k0 + 1) * 49 + ij];
    w3f[f] = pack_rne(f0, f1);
  } else {
    int k = (blk - 98) * 256 + t;
    if (k < 288) {
      int c = k / 9, r = k - c * 9;
      float s = 0.f;
#pragma unroll
      for (int o = 0; o < 32; ++o) s += w2[o] * w1[o * 288 + c * 9 + r];
      wk[k] = s;
    } else if (k == 288) {
      float s = b2[0];
#pragma unroll
      for (int o = 0; o < 32; ++o) s += w2[o] * b1[o];
      wk[288] = s;
    }
  }
}

// Fused kernel: one 8x8 pixel tile per block; 512 blocks x 512 threads (8 waves).
__global__ __launch_bounds__(512, 4) void fused_kernel(
    const float* __restrict__ x, const float* __restrict__ wk,
    const unsigned int* __restrict__ w3f, const float* __restrict__ b3,
    float* __restrict__ out, float* __restrict__ att_out) {
  // regA: phase1-1b = xs16 bf16 planar [c][sp] (8192 u16); phase2+ = as_ g-tile.
  __shared__ __align__(16) char regA[16384];
  unsigned short* xs16 = (unsigned short*)regA;   // xs16[c*256 + sp]
  float* as_ = (float*)regA;                      // as_[pos*68 + px] = 1+att
  __shared__ __align__(16) unsigned short xh[224 * 40];  // bf16 x [sp'][c], rows 1..14
  // ysb stride 17 (14 rows x 17, 238/dd): odd stride kills the py*16 two-bank
  // aliasing in phase 2's scattered u16 reads (R1 profile: 550k conflict cyc).
  __shared__ unsigned short ysb[9 * 238];         // bf16 y[dd][(r-1)*17+cc]
  __shared__ float wks[289];

  int t = threadIdx.x;
  int bi = blockIdx.x;
  int b = bi >> 8;
  int tile = bi & 255;
  int y0 = (tile >> 4) << 3, x0 = (tile & 15) << 3;
  const float* xb = x + ((long)b << 19);

  // phase-3 wave decomposition (needed early for the bw prefetch)
  int wv = t >> 6, lane = t & 63;
  int mt = wv >> 1, th = wv & 1;
  int ml = lane & 15, q = lane >> 4;
  const u32x4* bp = reinterpret_cast<const u32x4*>(w3f) + lane;
  // ---- bw prefetch: first two taps of this wave's parity (w3f is ready;
  // phases 1-2 hide the L2 latency; +16 VGPR on a 56-VGPR kernel) ----
  u32x4 pw0 = bp[th * 128];
  u32x4 pw1 = bp[th * 128 + 64];
  u32x4 pw2 = bp[(th + 2) * 128];
  u32x4 pw3 = bp[(th + 2) * 128 + 64];

  for (int k = t; k < 289; k += 512) wks[k] = wk[k];

  // ---- phase 1: global f32x4 -> bf16 -> planar xs16 (conflict-free b64) ----
#pragma unroll
  for (int it = 0; it < 4; ++it) {
    int idx = it * 512 + t;
    int c = idx >> 6;                 // wave-uniform
    int r64 = idx & 63;               // 4-pixel segment id; sp = 4*r64
    int row = r64 >> 2, seg = r64 & 3;
    int gy = y0 + row - 4;
    int gxs = x0 + (seg << 2) - 4;
    f32x4 v = {0.f, 0.f, 0.f, 0.f};
    if ((unsigned)gy < 128u && (unsigned)gxs < 128u)
      v = *reinterpret_cast<const f32x4*>(xb + (c << 14) + (gy << 7) + gxs);
    u32x2 p;
    p[0] = pack_rhu(v[0], v[1]);
    p[1] = pack_rhu(v[2], v[3]);
    *reinterpret_cast<u32x2*>(reinterpret_cast<unsigned int*>(xs16) +
                              (c << 7) + (r64 << 1)) = p;
  }
  __syncthreads();

  // ---- phase 1b (all 8 waves; thread -> pixel, dd-split): y[9] + xh pack ----
  // t<256: dd 0-3 + transpose-pack xh; t>=256: dd 4-8. Balances the previously
  // idle waves 4-7 against the 288-FMA lower half.
  {
    int p = t & 255;
    bool hi = t >= 256;
    int r = p >> 4;
    bool inner = (unsigned)(r - 1) < 14u;   // rows 1..14 are the used window
    int n = p - 16;                         // rebased row-major index
    int n17 = n + (n >> 4);                 // row*17 + col
    unsigned int u[32];
#pragma unroll
    for (int c = 0; c < 32; ++c) u[c] = xs16[(c << 8) + p];
    if (!hi) {
      float s[4];
#pragma unroll
      for (int dd = 0; dd < 4; ++dd) s[dd] = 0.f;
#pragma unroll
      for (int c = 0; c < 32; ++c) {
        float xf = bf16_to_f32(u[c]);
#pragma unroll
        for (int dd = 0; dd < 4; ++dd) s[dd] += xf * wks[c * 9 + dd];
      }
      if (inner) {
#pragma unroll
        for (int dd = 0; dd < 4; ++dd)
          ysb[dd * 238 + n17] = (unsigned short)(bf16_rhu(s[dd]) >> 16);
        unsigned int* xhd = reinterpret_cast<unsigned int*>(xh) + n * 20;
#pragma unroll
        for (int g4 = 0; g4 < 4; ++g4) {
          u32x4 d;
#pragma unroll
          for (int e = 0; e < 4; ++e) {
            int k2 = g4 * 4 + e;
            d[e] = __builtin_amdgcn_perm(u[2 * k2 + 1], u[2 * k2], 0x05040100u);
          }
          *reinterpret_cast<u32x4*>(xhd + g4 * 4) = d;
        }
      }
    } else {
      float s[5];
#pragma unroll
      for (int dd = 0; dd < 5; ++dd) s[dd] = 0.f;
#pragma unroll
      for (int c = 0; c < 32; ++c) {
        float xf = bf16_to_f32(u[c]);
#pragma unroll
        for (int dd = 0; dd < 5; ++dd) s[dd] += xf * wks[c * 9 + 4 + dd];
      }
      if (inner) {
#pragma unroll
        for (int dd = 0; dd < 5; ++dd)
          ysb[(4 + dd) * 238 + n17] = (unsigned short)(bf16_rhu(s[dd]) >> 16);
      }
    }
  }
  __syncthreads();

  // ---- phase 2: as_[pos][px] = 1 + sigmoid(bk + sum_valid y) ----
#pragma unroll 1
  for (int it = 0; it < 7; ++it) {
    int f = it * 512 + t;
    if (f < 3136) {
      int pos = f >> 6;               // wave-uniform
      int px = f & 63;
      int py = px >> 3, pxl = px & 7;
      int i = pos / 7, j = pos - i * 7;
      float s = wks[288];
#pragma unroll
      for (int di = 0; di < 3; ++di) {
        int ii = i + di - 1;
        if ((unsigned)ii >= 7u) continue;
#pragma unroll
        for (int dj = 0; dj < 3; ++dj) {
          int jj = j + dj - 1;
          if ((unsigned)jj >= 7u) continue;
          s += bf16_to_f32(
              (unsigned int)ysb[(di * 3 + dj) * 238 + (py + ii) * 17 + pxl + jj + 1]);
        }
      }
      // fast sigmoid: v_exp_f32 + v_rcp_f32 (err ~1e-6, << bf16 rounding)
      float e = __expf(-s);
      as_[pos * 68 + px] = 1.f + __builtin_amdgcn_rcpf(1.f + e);
    }
  }
  __syncthreads();

  // ---- phase 2.5: coalesced att_out stores (att = g - 1) ----
#pragma unroll 1
  for (int it = 0; it < 7; ++it) {
    int f = it * 512 + t;
    if (f < 3136) {
      int row = f / 392;
      int rem = f - row * 392;
      int pxl = rem / 49;
      int pos = rem - pxl * 49;
      long base = ((long)(b << 14) + ((y0 + row) << 7) + x0) * 49;
      att_out[base + rem] = as_[pos * 68 + (row << 3) + pxl] - 1.f;
    }
  }

  // ---- phase 3: wave w -> m-tile (w>>1), tap-parity (w&1); both o-halves ----
  // Tap-split: af and gv are read once per tap per m-tile instead of twice.
  int px = mt * 16 + ml;               // A-row pixel for this lane
  int py = px >> 3, pxl = px & 7;
  f32x4 acc0 = {0.f, 0.f, 0.f, 0.f};   // o = ml      (oh=0 half)
  f32x4 acc1 = {0.f, 0.f, 0.f, 0.f};   // o = 16 + ml (oh=1 half)
  auto tapw = [&](int ij, u32x4 bw0, u32x4 bw1) {
    int i = (ij * 37) >> 8;            // ij/7 for ij in [0,48]
    int j = ij - i * 7;
    int nb = (py + i) * 16 + pxl + 1 + j;
    bf16x8 af = *reinterpret_cast<const bf16x8*>(&xh[nb * 40 + (q << 3)]);
    f32x4 gv = *reinterpret_cast<const f32x4*>(&as_[ij * 68 + mt * 16 + (q << 2)]);
    f32x4 z = {0.f, 0.f, 0.f, 0.f};
    // setprio around the MFMA+gating cluster (T5): the co-resident block on
    // this CU is in a VALU phase -> prioritize the matrix-feeding wave.
    __builtin_amdgcn_s_setprio(1);
    f32x4 P0 = __builtin_amdgcn_mfma_f32_16x16x32_bf16(
        af, __builtin_bit_cast(bf16x8, bw0), z, 0, 0, 0);
    f32x4 P1 = __builtin_amdgcn_mfma_f32_16x16x32_bf16(
        af, __builtin_bit_cast(bf16x8, bw1), z, 0, 0, 0);
#pragma unroll
    for (int r = 0; r < 4; ++r) {
      acc0[r] += gv[r] * P0[r];
      acc1[r] += gv[r] * P1[r];
    }
    __builtin_amdgcn_s_setprio(0);
  };
  auto tap = [&](int ij) { tapw(ij, bp[ij * 128], bp[ij * 128 + 64]); };
  // peeled: prefetched taps {th, th+2}
  tapw(th, pw0, pw1);
  tapw(th + 2, pw2, pw3);
  if (th == 0) {
#pragma unroll 3
    for (int k = 2; k < 25; ++k) tap(2 * k);        // even taps 4..48
  } else {
#pragma unroll 3
    for (int k = 2; k < 24; ++k) tap(2 * k + 1);    // odd taps 5..47
  }
  __syncthreads();   // all gv/af reads done; reuse as_ for the output transpose

  // ---- epilogue: two-step parity reduction into as_[o][px] ----
  {
    int o0 = ml, o1 = 16 + ml;
    int base = mt * 16 + (q << 2);
    if (th == 0) {
      float bv0 = b3[o0], bv1 = b3[o1];
#pragma unroll
      for (int r = 0; r < 4; ++r) {
        as_[o0 * 68 + base + r] = acc0[r] + bv0;
        as_[o1 * 68 + base + r] = acc1[r] + bv1;
      }
    }
    __syncthreads();
    if (th == 1) {
#pragma unroll
      for (int r = 0; r < 4; ++r) {
        as_[o0 * 68 + base + r] += acc0[r];
        as_[o1 * 68 + base + r] += acc1[r];
      }
    }
  }
  __syncthreads();
#pragma unroll
  for (int rep = 0; rep < 4; ++rep) {
    int idx = rep * 512 + t;
    int o = idx >> 6, pxs = idx & 63;
    out[((long)b << 19) + (o << 14) + ((y0 + (pxs >> 3)) << 7) + x0 + (pxs & 7)]
        = as_[o * 68 + pxs];
  }
}

extern "C" void kernel_launch(void* const* d_in, const int* in_sizes, int n_in,
                              void* d_out, int out_size, void* d_ws, size_t ws_size,
                              hipStream_t stream) {
  const float* x  = (const float*)d_in[0];
  const float* w1 = (const float*)d_in[1];
  const float* b1 = (const float*)d_in[2];
  const float* w2 = (const float*)d_in[3];
  const float* b2 = (const float*)d_in[4];
  const float* w3 = (const float*)d_in[5];
  const float* b3 = (const float*)d_in[6];

  float* out = (float*)d_out;
  float* att_out = out + OUT0;
  float* wk = (float*)d_ws;                                // 289 floats
  unsigned int* w3f = (unsigned int*)((char*)d_ws + 4096); // 25088 dwords

  prep_kernel<<<100, 256, 0, stream>>>(w1, b1, w2, b2, w3, wk, w3f);
  fused_kernel<<<512, 512, 0, stream>>>(x, wk, w3f, b3, out, att_out);
}

// Round 4
// 89.532 us; speedup vs baseline: 1.4022x; 1.4022x over previous
//
#include <hip/hip_runtime.h>

typedef __attribute__((ext_vector_type(8))) short bf16x8;
typedef __attribute__((ext_vector_type(4))) float f32x4;
typedef __attribute__((ext_vector_type(4))) unsigned int u32x4;
typedef __attribute__((ext_vector_type(2))) unsigned int u32x2;

namespace {
constexpr int OUT0 = 2 * 32 * 16384;  // offset of att_mp inside d_out
}

// f32 -> bf16 RNE (pre-shift: result in high 16 bits)
__device__ __forceinline__ unsigned int bf16_rne(float f) {
  unsigned int u = __builtin_bit_cast(unsigned int, f);
  return u + 0x7fffu + ((u >> 16) & 1u);
}
// f32 -> bf16 round-half-up (1 VALU; tie-bias only)
__device__ __forceinline__ unsigned int bf16_rhu(float f) {
  return __builtin_bit_cast(unsigned int, f) + 0x8000u;
}
__device__ __forceinline__ unsigned int pack_rne(float lo, float hi) {
  return __builtin_amdgcn_perm(bf16_rne(hi), bf16_rne(lo), 0x07060302u);
}
__device__ __forceinline__ unsigned int pack_rhu(float lo, float hi) {
  return __builtin_amdgcn_perm(bf16_rhu(hi), bf16_rhu(lo), 0x07060302u);
}
__device__ __forceinline__ float bf16_to_f32(unsigned int u16v) {
  return __builtin_bit_cast(float, u16v << 16);
}

// Prep: (a) pack w3 into per-lane bf16 B-fragments for mfma_f32_16x16x32_bf16:
//   u32x4 index = ij*128 + oh*64 + lane; dword d: B[k0][o],B[k0+1][o],
//   k(=c) = (lane>>4)*8 + 2d, o = oh*16 + (lane&15).
// (b) wk[c*9+dd] = sum_o w2[o]*w1[o,c,dd]; wk[288] = w2.b1 + b2.
//
// SESSION NOTES (do not re-try):
//  R1: single-kernel fusion w/ flag sync: 89->179us. Agent-scope fences on
//      gfx950 do L2 writeback+invalidate (per-XCD L2 non-coherent) -> all
//      blocks stall. Two-kernel split is structurally cheaper.
//  R3: bw-prefetch regs + all-wave u[32] in phase 1b: scratch spill
//      (WRITE_SIZE 10.4->87MB), fused 29->52us. Keep peak VGPR pressure low;
//      no values held across phases beyond the baseline set.
//  R2: tap-split phase 3 (halved af/gv LDS reads): neutral vs R0 -> phase 3
//      LDS issue is not the critical path; fused is latency/boundary-bound.
__global__ __launch_bounds__(256) void prep_kernel(
    const float* __restrict__ w1, const float* __restrict__ b1,
    const float* __restrict__ w2, const float* __restrict__ b2,
    const float* __restrict__ w3,
    float* __restrict__ wk, unsigned int* __restrict__ w3f) {
  int t = threadIdx.x, blk = blockIdx.x;
  if (blk < 98) {
    int f = blk * 256 + t;          // dword index, f < 25088
    int d = f & 3;
    int lane = (f >> 2) & 63;
    int nt = (f >> 8) & 1;
    int ij = f >> 9;                // 0..48
    int o = nt * 16 + (lane & 15);
    int k0 = ((lane >> 4) << 3) + 2 * d;
    float f0 = w3[o * 1568 + k0 * 49 + ij];
    float f1 = w3[o * 1568 + (k0 + 1) * 49 + ij];
    w3f[f] = pack_rne(f0, f1);
  } else {
    int k = (blk - 98) * 256 + t;
    if (k < 288) {
      int c = k / 9, r = k - c * 9;
      float s = 0.f;
#pragma unroll
      for (int o = 0; o < 32; ++o) s += w2[o] * w1[o * 288 + c * 9 + r];
      wk[k] = s;
    } else if (k == 288) {
      float s = b2[0];
#pragma unroll
      for (int o = 0; o < 32; ++o) s += w2[o] * b1[o];
      wk[288] = s;
    }
  }
}

// Fused kernel: one 8x8 pixel tile per block; 512 blocks x 512 threads (8 waves).
__global__ __launch_bounds__(512, 4) void fused_kernel(
    const float* __restrict__ x, const float* __restrict__ wk,
    const unsigned int* __restrict__ w3f, const float* __restrict__ b3,
    float* __restrict__ out, float* __restrict__ att_out) {
  // regA: phase1-1b = xs16 bf16 planar [c][sp] (8192 u16); phase2+ = as_ g-tile.
  __shared__ __align__(16) char regA[16384];
  unsigned short* xs16 = (unsigned short*)regA;   // xs16[c*256 + sp]
  float* as_ = (float*)regA;                      // as_[pos*68 + px] = 1+att
  __shared__ __align__(16) unsigned short xh[224 * 40];  // bf16 x [sp'][c], rows 1..14
  // ysb stride 17 (14 rows x 17 per dd): odd stride breaks the py*16 bank
  // aliasing in phase 2's scattered u16 reads (R1 profile: 550k conflict cyc).
  __shared__ unsigned short ysb[9 * 238];         // bf16 y[dd][(r-1)*17+cc]
  __shared__ float wks[289];

  int t = threadIdx.x;
  int bi = blockIdx.x;
  int b = bi >> 8;
  int tile = bi & 255;
  int y0 = (tile >> 4) << 3, x0 = (tile & 15) << 3;
  const float* xb = x + ((long)b << 19);

  for (int k = t; k < 289; k += 512) wks[k] = wk[k];

  // ---- phase 1: global f32x4 -> bf16 -> planar xs16 (conflict-free b64) ----
#pragma unroll
  for (int it = 0; it < 4; ++it) {
    int idx = it * 512 + t;
    int c = idx >> 6;                 // wave-uniform
    int r64 = idx & 63;               // 4-pixel segment id; sp = 4*r64
    int row = r64 >> 2, seg = r64 & 3;
    int gy = y0 + row - 4;
    int gxs = x0 + (seg << 2) - 4;
    f32x4 v = {0.f, 0.f, 0.f, 0.f};
    if ((unsigned)gy < 128u && (unsigned)gxs < 128u)
      v = *reinterpret_cast<const f32x4*>(xb + (c << 14) + (gy << 7) + gxs);
    u32x2 p;
    p[0] = pack_rhu(v[0], v[1]);
    p[1] = pack_rhu(v[2], v[3]);
    *reinterpret_cast<u32x2*>(reinterpret_cast<unsigned int*>(xs16) +
                              (c << 7) + (r64 << 1)) = p;
  }
  __syncthreads();

  // ---- phase 1b (t<256, thread=pixel): y[9] + transpose-pack xh ----
  if (t < 256) {
    int r = t >> 4;
    bool inner = (unsigned)(r - 1) < 14u;   // rows 1..14 are the used window
    int n = t - 16;                         // rebased row-major index
    int n17 = n + (n >> 4);                 // (r-1)*17 + cc
    unsigned int u[32];
#pragma unroll
    for (int c = 0; c < 32; ++c) u[c] = xs16[(c << 8) + t];
    float s[9];
#pragma unroll
    for (int dd = 0; dd < 9; ++dd) s[dd] = 0.f;
#pragma unroll
    for (int c = 0; c < 32; ++c) {
      float xf = bf16_to_f32(u[c]);
#pragma unroll
      for (int dd = 0; dd < 9; ++dd) s[dd] += xf * wks[c * 9 + dd];
    }
    if (inner) {
#pragma unroll
      for (int dd = 0; dd < 9; ++dd)
        ysb[dd * 238 + n17] = (unsigned short)(bf16_rhu(s[dd]) >> 16);
      unsigned int* xhd = reinterpret_cast<unsigned int*>(xh) + n * 20;
#pragma unroll
      for (int g4 = 0; g4 < 4; ++g4) {
        u32x4 d;
#pragma unroll
        for (int e = 0; e < 4; ++e) {
          int k2 = g4 * 4 + e;
          d[e] = __builtin_amdgcn_perm(u[2 * k2 + 1], u[2 * k2], 0x05040100u);
        }
        *reinterpret_cast<u32x4*>(xhd + g4 * 4) = d;
      }
    }
  }
  __syncthreads();

  // ---- phase 2: as_[pos][px] = 1 + sigmoid(bk + sum_valid y) ----
#pragma unroll 1
  for (int it = 0; it < 7; ++it) {
    int f = it * 512 + t;
    if (f < 3136) {
      int pos = f >> 6;               // wave-uniform
      int px = f & 63;
      int py = px >> 3, pxl = px & 7;
      int i = pos / 7, j = pos - i * 7;
      float s = wks[288];
#pragma unroll
      for (int di = 0; di < 3; ++di) {
        int ii = i + di - 1;
        if ((unsigned)ii >= 7u) continue;
#pragma unroll
        for (int dj = 0; dj < 3; ++dj) {
          int jj = j + dj - 1;
          if ((unsigned)jj >= 7u) continue;
          s += bf16_to_f32(
              (unsigned int)ysb[(di * 3 + dj) * 238 + (py + ii) * 17 + pxl + jj + 1]);
        }
      }
      // fast sigmoid: v_exp_f32 + v_rcp_f32 (err ~1e-6, << bf16 rounding)
      float e = __expf(-s);
      as_[pos * 68 + px] = 1.f + __builtin_amdgcn_rcpf(1.f + e);
    }
  }
  __syncthreads();

  // ---- phase 2.5: coalesced att_out stores (att = g - 1) ----
#pragma unroll 1
  for (int it = 0; it < 7; ++it) {
    int f = it * 512 + t;
    if (f < 3136) {
      int row = f / 392;
      int rem = f - row * 392;
      int pxl = rem / 49;
      int pos = rem - pxl * 49;
      long base = ((long)(b << 14) + ((y0 + row) << 7) + x0) * 49;
      att_out[base + rem] = as_[pos * 68 + (row << 3) + pxl] - 1.f;
    }
  }

  // ---- phase 3: wave w -> m-tile (w>>1), o-half (w&1); 1 MFMA per tap ----
  int wv = t >> 6, lane = t & 63;
  int mt = wv >> 1, oh = wv & 1;
  int ml = lane & 15, q = lane >> 4;
  int px = mt * 16 + ml;               // A-row pixel for this lane
  int py = px >> 3, pxl = px & 7;
  f32x4 acc = {0.f, 0.f, 0.f, 0.f};
  const u32x4* bp = reinterpret_cast<const u32x4*>(w3f) + lane + oh * 64;
#pragma unroll 1
  for (int i = 0; i < 7; ++i) {
    int nb = (py + i) * 16 + pxl + 1;
#pragma unroll
    for (int j = 0; j < 7; ++j) {
      int ij = i * 7 + j;
      u32x4 bw = bp[ij * 128];
      bf16x8 af = *reinterpret_cast<const bf16x8*>(&xh[(nb + j) * 40 + (q << 3)]);
      f32x4 gv = *reinterpret_cast<const f32x4*>(&as_[ij * 68 + mt * 16 + (q << 2)]);
      f32x4 z = {0.f, 0.f, 0.f, 0.f};
      f32x4 P = __builtin_amdgcn_mfma_f32_16x16x32_bf16(
          af, __builtin_bit_cast(bf16x8, bw), z, 0, 0, 0);
#pragma unroll
      for (int r = 0; r < 4; ++r) acc[r] += gv[r] * P[r];
    }
  }
  __syncthreads();   // g-reads done; reuse as_ for the output transpose

  // ---- epilogue: D col=lane&15 -> o = oh*16+ml, row=q*4+r -> px ----
  {
    int o = oh * 16 + ml;
    float bv = b3[o];
#pragma unroll
    for (int r = 0; r < 4; ++r)
      as_[o * 68 + mt * 16 + (q << 2) + r] = acc[r] + bv;
  }
  __syncthreads();
#pragma unroll
  for (int rep = 0; rep < 4; ++rep) {
    int idx = rep * 512 + t;
    int o = idx >> 6, pxs = idx & 63;
    out[((long)b << 19) + (o << 14) + ((y0 + (pxs >> 3)) << 7) + x0 + (pxs & 7)]
        = as_[o * 68 + pxs];
  }
}

extern "C" void kernel_launch(void* const* d_in, const int* in_sizes, int n_in,
                              void* d_out, int out_size, void* d_ws, size_t ws_size,
                              hipStream_t stream) {
  const float* x  = (const float*)d_in[0];
  const float* w1 = (const float*)d_in[1];
  const float* b1 = (const float*)d_in[2];
  const float* w2 = (const float*)d_in[3];
  const float* b2 = (const float*)d_in[4];
  const float* w3 = (const float*)d_in[5];
  const float* b3 = (const float*)d_in[6];

  float* out = (float*)d_out;
  float* att_out = out + OUT0;
  float* wk = (float*)d_ws;                                // 289 floats
  unsigned int* w3f = (unsigned int*)((char*)d_ws + 4096); // 25088 dwords

  prep_kernel<<<100, 256, 0, stream>>>(w1, b1, w2, b2, w3, wk, w3f);
  fused_kernel<<<512, 512, 0, stream>>>(x, wk, w3f, b3, out, att_out);
}